// Round 1
// baseline (182.817 us; speedup 1.0000x reference)
//
#include <hip/hip_runtime.h>
#include <hip/hip_bf16.h>

// Problem constants (from reference)
#define BATCH   16
#define OUT_C   256
#define KK      3
#define Z_DIM   64
#define H_DIM   128
#define W_DIM   128

// ---------------------------------------------------------------------------
// Kernel 1: W_dw[b, j] = dot(z[b, :], W_lin[j, :])   j in [0, OUT_C*K*K)
// Tiny: 36,864 outputs x 64 MACs. float4-vectorized.
// ---------------------------------------------------------------------------
__global__ void hyper_gemm_kernel(const float* __restrict__ z,
                                  const float* __restrict__ W_lin,
                                  float* __restrict__ wdw) {
    const int tid = blockIdx.x * blockDim.x + threadIdx.x;
    const int total = BATCH * OUT_C * KK * KK;   // 36864
    if (tid >= total) return;
    const int b = tid / (OUT_C * KK * KK);
    const int j = tid - b * (OUT_C * KK * KK);

    const float4* zr = reinterpret_cast<const float4*>(z + b * Z_DIM);
    const float4* wr = reinterpret_cast<const float4*>(W_lin + (size_t)j * Z_DIM);

    float acc = 0.f;
#pragma unroll
    for (int i = 0; i < Z_DIM / 4; ++i) {
        float4 a = zr[i];
        float4 w = wr[i];
        acc += a.x * w.x + a.y * w.y + a.z * w.z + a.w * w.w;
    }
    wdw[tid] = acc;
}

// ---------------------------------------------------------------------------
// Kernel 2: depthwise 3x3 conv, pad 1, per-sample weights.
// One block = one (b,c) plane x 32-row slab. 256 threads:
//   tcol = tid & 31  -> 4 consecutive cols each (32*4 = 128 = W)
//   trow = tid >> 5  -> 8 rows concurrently, 4 passes = 32 rows
// Each output row: 1 float4 + 2 boundary scalars per input row, 9 FMAs/out.
// ---------------------------------------------------------------------------
#define ROWS_PER_BLOCK 32

__global__ __launch_bounds__(256)
void dwconv3x3_kernel(const float* __restrict__ x,
                      const float* __restrict__ wdw,
                      float* __restrict__ out) {
    const int rowblk = blockIdx.x & (H_DIM / ROWS_PER_BLOCK - 1);   // 0..3
    const int plane  = blockIdx.x >> 2;                             // b*OUT_C + c

    const float* __restrict__ xin  = x   + (size_t)plane * (H_DIM * W_DIM);
    float*       __restrict__ oout = out + (size_t)plane * (H_DIM * W_DIM);

    // 9 per-plane weights — uniform address, compiler emits scalar loads.
    const float* __restrict__ wp = wdw + (size_t)plane * (KK * KK);
    const float w00 = wp[0], w01 = wp[1], w02 = wp[2];
    const float w10 = wp[3], w11 = wp[4], w12 = wp[5];
    const float w20 = wp[6], w21 = wp[7], w22 = wp[8];

    const int tcol = threadIdx.x & 31;
    const int trow = threadIdx.x >> 5;
    const int c0   = tcol * 4;                                      // 0..124

#pragma unroll
    for (int rr = 0; rr < ROWS_PER_BLOCK / 8; ++rr) {
        const int r = rowblk * ROWS_PER_BLOCK + rr * 8 + trow;

        float a0 = 0.f, a1 = 0.f, a2 = 0.f, a3 = 0.f;

#pragma unroll
        for (int dr = -1; dr <= 1; ++dr) {
            const int ir = r + dr;
            if (ir < 0 || ir >= H_DIM) continue;
            const float* rowp = xin + ir * W_DIM;

            const float4 mid = *reinterpret_cast<const float4*>(rowp + c0);
            const float  lf  = (c0 > 0)          ? rowp[c0 - 1] : 0.f;
            const float  rt  = (c0 + 4 < W_DIM)  ? rowp[c0 + 4] : 0.f;

            float wa, wb, wc;
            if (dr == -1)      { wa = w00; wb = w01; wc = w02; }
            else if (dr == 0)  { wa = w10; wb = w11; wc = w12; }
            else               { wa = w20; wb = w21; wc = w22; }

            const float i0 = lf, i1 = mid.x, i2 = mid.y, i3 = mid.z,
                        i4 = mid.w, i5 = rt;

            a0 = fmaf(wa, i0, fmaf(wb, i1, fmaf(wc, i2, a0)));
            a1 = fmaf(wa, i1, fmaf(wb, i2, fmaf(wc, i3, a1)));
            a2 = fmaf(wa, i2, fmaf(wb, i3, fmaf(wc, i4, a2)));
            a3 = fmaf(wa, i3, fmaf(wb, i4, fmaf(wc, i5, a3)));
        }

        float4 res;
        res.x = a0; res.y = a1; res.z = a2; res.w = a3;
        *reinterpret_cast<float4*>(oout + r * W_DIM + c0) = res;
    }
}

// ---------------------------------------------------------------------------
extern "C" void kernel_launch(void* const* d_in, const int* in_sizes, int n_in,
                              void* d_out, int out_size, void* d_ws, size_t ws_size,
                              hipStream_t stream) {
    const float* x     = (const float*)d_in[0];   // (B, C, H, W)
    const float* z     = (const float*)d_in[1];   // (B, Z)
    const float* W_lin = (const float*)d_in[2];   // (C*K*K, Z)
    float* out = (float*)d_out;
    float* wdw = (float*)d_ws;                    // (B, C*K*K) = 36864 floats

    // Stage 1: hypernetwork weights
    {
        const int total = BATCH * OUT_C * KK * KK;  // 36864
        const int blk = 256;
        hyper_gemm_kernel<<<(total + blk - 1) / blk, blk, 0, stream>>>(z, W_lin, wdw);
    }

    // Stage 2: depthwise conv
    {
        const int grid = BATCH * OUT_C * (H_DIM / ROWS_PER_BLOCK);  // 16384
        dwconv3x3_kernel<<<grid, 256, 0, stream>>>(x, wdw, out);
    }
}

// Round 3
// 135.184 us; speedup vs baseline: 1.3524x; 1.3524x over previous
//
#include <hip/hip_runtime.h>
#include <hip/hip_bf16.h>

// Problem constants (from reference)
#define BATCH   16
#define OUT_C   256
#define KK      3
#define Z_DIM   64
#define H_DIM   128
#define W_DIM   128

typedef float vf4 __attribute__((ext_vector_type(4)));   // clang-native vec4

// ---------------------------------------------------------------------------
// Kernel 1: W_dw[b, j] = dot(z[b, :], W_lin[j, :])   j in [0, OUT_C*K*K)
// Tiny: 36,864 outputs x 64 MACs. float4-vectorized.
// ---------------------------------------------------------------------------
__global__ void hyper_gemm_kernel(const float* __restrict__ z,
                                  const float* __restrict__ W_lin,
                                  float* __restrict__ wdw) {
    const int tid = blockIdx.x * blockDim.x + threadIdx.x;
    const int total = BATCH * OUT_C * KK * KK;   // 36864
    if (tid >= total) return;
    const int b = tid / (OUT_C * KK * KK);
    const int j = tid - b * (OUT_C * KK * KK);

    const vf4* zr = reinterpret_cast<const vf4*>(z + b * Z_DIM);
    const vf4* wr = reinterpret_cast<const vf4*>(W_lin + (size_t)j * Z_DIM);

    float acc = 0.f;
#pragma unroll
    for (int i = 0; i < Z_DIM / 4; ++i) {
        vf4 a = zr[i];
        vf4 w = wr[i];
        acc += a.x * w.x + a.y * w.y + a.z * w.z + a.w * w.w;
    }
    wdw[tid] = acc;
}

// ---------------------------------------------------------------------------
// Kernel 2: depthwise 3x3 conv, pad 1, per-sample weights.
// Register sliding-window version.
//
// One block per (b,c) plane. 256 threads = 16 col-groups x 16 row-groups.
//   tcol = tid & 15  -> 8 consecutive cols each (16*8 = 128 = W)
//   trow = tid >> 4  -> 8 consecutive rows each (16*8 = 128 = H)
// Each thread slides a 3-row x 10-float register window down its 8 output
// rows: every input row is loaded from global exactly once (2x float4 + 2
// boundary scalars), giving ~0.9 VMEM instr / output (vs 2.5 in round 0)
// and forcing enough VGPRs (~60) that multiple row-loads stay in flight.
// ---------------------------------------------------------------------------
struct Row10 { float v[10]; };   // v[0] = col c0-1, v[1..8] = c0..c0+7, v[9] = c0+8

__device__ __forceinline__ Row10 load_row(const float* __restrict__ xin,
                                          int ir, int c0) {
    Row10 r;
    if (ir < 0 || ir >= H_DIM) {
#pragma unroll
        for (int i = 0; i < 10; ++i) r.v[i] = 0.f;
        return r;
    }
    const float* p = xin + ir * W_DIM + c0;
    const vf4 m0 = *reinterpret_cast<const vf4*>(p);
    const vf4 m1 = *reinterpret_cast<const vf4*>(p + 4);
    r.v[0] = (c0 > 0)           ? p[-1] : 0.f;
    r.v[1] = m0.x; r.v[2] = m0.y; r.v[3] = m0.z; r.v[4] = m0.w;
    r.v[5] = m1.x; r.v[6] = m1.y; r.v[7] = m1.z; r.v[8] = m1.w;
    r.v[9] = (c0 + 8 < W_DIM)   ? p[8]  : 0.f;
    return r;
}

__global__ __launch_bounds__(256)
void dwconv3x3_kernel(const float* __restrict__ x,
                      const float* __restrict__ wdw,
                      float* __restrict__ out) {
    const int plane = blockIdx.x;                                  // b*OUT_C + c

    const float* __restrict__ xin  = x   + (size_t)plane * (H_DIM * W_DIM);
    float*       __restrict__ oout = out + (size_t)plane * (H_DIM * W_DIM);

    // 9 per-plane weights — uniform address, scalar loads.
    const float* __restrict__ wp = wdw + (size_t)plane * (KK * KK);
    const float w00 = wp[0], w01 = wp[1], w02 = wp[2];
    const float w10 = wp[3], w11 = wp[4], w12 = wp[5];
    const float w20 = wp[6], w21 = wp[7], w22 = wp[8];

    const int tcol = threadIdx.x & 15;
    const int trow = threadIdx.x >> 4;
    const int c0   = tcol * 8;          // 0..120
    const int r0   = trow * 8;          // 0..120

    Row10 A = load_row(xin, r0 - 1, c0);   // row above (zeros at plane top)
    Row10 B = load_row(xin, r0,     c0);

#pragma unroll
    for (int j = 0; j < 8; ++j) {
        const Row10 C = load_row(xin, r0 + j + 1, c0);   // next row (zeros at bottom)

        float o[8];
#pragma unroll
        for (int k = 0; k < 8; ++k) {
            float a;
            a = fmaf(w00, A.v[k], fmaf(w01, A.v[k + 1], w02 * A.v[k + 2]));
            a = fmaf(w10, B.v[k], fmaf(w11, B.v[k + 1], fmaf(w12, B.v[k + 2], a)));
            a = fmaf(w20, C.v[k], fmaf(w21, C.v[k + 1], fmaf(w22, C.v[k + 2], a)));
            o[k] = a;
        }

        vf4 s0, s1;
        s0.x = o[0]; s0.y = o[1]; s0.z = o[2]; s0.w = o[3];
        s1.x = o[4]; s1.y = o[5]; s1.z = o[6]; s1.w = o[7];
        float* op = oout + (r0 + j) * W_DIM + c0;
        __builtin_nontemporal_store(s0, reinterpret_cast<vf4*>(op));
        __builtin_nontemporal_store(s1, reinterpret_cast<vf4*>(op + 4));

        A = B;
        B = C;
    }
}

// ---------------------------------------------------------------------------
extern "C" void kernel_launch(void* const* d_in, const int* in_sizes, int n_in,
                              void* d_out, int out_size, void* d_ws, size_t ws_size,
                              hipStream_t stream) {
    const float* x     = (const float*)d_in[0];   // (B, C, H, W)
    const float* z     = (const float*)d_in[1];   // (B, Z)
    const float* W_lin = (const float*)d_in[2];   // (C*K*K, Z)
    float* out = (float*)d_out;
    float* wdw = (float*)d_ws;                    // (B, C*K*K) = 36864 floats

    // Stage 1: hypernetwork weights
    {
        const int total = BATCH * OUT_C * KK * KK;  // 36864
        const int blk = 256;
        hyper_gemm_kernel<<<(total + blk - 1) / blk, blk, 0, stream>>>(z, W_lin, wdw);
    }

    // Stage 2: depthwise conv — one block per (b,c) plane
    {
        const int grid = BATCH * OUT_C;             // 4096
        dwconv3x3_kernel<<<grid, 256, 0, stream>>>(x, wdw, out);
    }
}